// Round 1
// baseline (851.942 us; speedup 1.0000x reference)
//
#include <hip/hip_runtime.h>
#include <math.h>

#define D_MODEL 256
#define N_HEADS 8
#define HEAD_DIM 32
#define D_FFN   1024
#define BB      4
#define NN      1024
#define M_TOT   (BB * NN)     // 4096 rows
#define LN_EPS  1e-5f

// ---------------------------------------------------------------------------
// K1: qk_in = embed + query_pos (elementwise, float4)
// ---------------------------------------------------------------------------
__global__ __launch_bounds__(256)
void add_kernel(const float* __restrict__ a, const float* __restrict__ b,
                float* __restrict__ o, int n4) {
    int i = blockIdx.x * blockDim.x + threadIdx.x;
    if (i < n4) {
        float4 x = ((const float4*)a)[i];
        float4 y = ((const float4*)b)[i];
        x.x += y.x; x.y += y.y; x.z += y.z; x.w += y.w;
        ((float4*)o)[i] = x;
    }
}

// ---------------------------------------------------------------------------
// K2: fused qkv + tau projection.
//   cols [0,256)  : q = qk_in @ wq^T + bq   -> qb[b][h][n][d]
//   cols [256,512): k = qk_in @ wk^T + bk   -> kb[b][h][n][d]
//   cols [512,768): v = embed @ wv^T + bv   -> vb[b][h][n][d]
//   cols [768,776): tau = embed @ tau_w^T + tau_b -> taub[b][h][n]
// Tiled 64x64, K-step 16, 256 threads, 4x4 accum per thread.
// ---------------------------------------------------------------------------
__global__ __launch_bounds__(256)
void qkv_kernel(const float* __restrict__ qk_in, const float* __restrict__ embed,
                const float* __restrict__ in_proj_w, const float* __restrict__ in_proj_b,
                const float* __restrict__ tau_w, const float* __restrict__ tau_b,
                float* __restrict__ qb, float* __restrict__ kb,
                float* __restrict__ vb, float* __restrict__ taub) {
    __shared__ float As[16][65];
    __shared__ float Bs[16][65];
    const int K = D_MODEL;
    const int n0 = blockIdx.x * 64;
    const int m0 = blockIdx.y * 64;
    const float* A = (blockIdx.x < 8) ? qk_in : embed;  // q,k tiles use embed+pos

    const int lrow = threadIdx.x >> 2;   // 0..63
    const int kq   = threadIdx.x & 3;    // 0..3
    const int tx = threadIdx.x & 15, ty = threadIdx.x >> 4;

    float acc[4][4] = {};
    for (int k0 = 0; k0 < K; k0 += 16) {
        float4 av = *(const float4*)&A[(size_t)(m0 + lrow) * K + k0 + kq * 4];
        As[kq*4+0][lrow] = av.x; As[kq*4+1][lrow] = av.y;
        As[kq*4+2][lrow] = av.z; As[kq*4+3][lrow] = av.w;

        const int c = n0 + lrow;
        float4 bv = make_float4(0.f, 0.f, 0.f, 0.f);
        if (c < 768)      bv = *(const float4*)&in_proj_w[(size_t)c * K + k0 + kq * 4];
        else if (c < 776) bv = *(const float4*)&tau_w[(size_t)(c - 768) * K + k0 + kq * 4];
        Bs[kq*4+0][lrow] = bv.x; Bs[kq*4+1][lrow] = bv.y;
        Bs[kq*4+2][lrow] = bv.z; Bs[kq*4+3][lrow] = bv.w;
        __syncthreads();

        #pragma unroll
        for (int k = 0; k < 16; k++) {
            float a0 = As[k][ty*4+0], a1 = As[k][ty*4+1], a2 = As[k][ty*4+2], a3 = As[k][ty*4+3];
            float b0 = Bs[k][tx*4+0], b1 = Bs[k][tx*4+1], b2 = Bs[k][tx*4+2], b3 = Bs[k][tx*4+3];
            acc[0][0] += a0*b0; acc[0][1] += a0*b1; acc[0][2] += a0*b2; acc[0][3] += a0*b3;
            acc[1][0] += a1*b0; acc[1][1] += a1*b1; acc[1][2] += a1*b2; acc[1][3] += a1*b3;
            acc[2][0] += a2*b0; acc[2][1] += a2*b1; acc[2][2] += a2*b2; acc[2][3] += a2*b3;
            acc[3][0] += a3*b0; acc[3][1] += a3*b1; acc[3][2] += a3*b2; acc[3][3] += a3*b3;
        }
        __syncthreads();
    }

    #pragma unroll
    for (int i = 0; i < 4; i++) {
        const int m = m0 + ty * 4 + i;
        const int b = m >> 10;          // / NN
        const int nrow = m & 1023;      // % NN
        #pragma unroll
        for (int j = 0; j < 4; j++) {
            const int c = n0 + tx * 4 + j;
            if (c >= 776) continue;
            const float bias = (c < 768) ? in_proj_b[c] : tau_b[c - 768];
            const float v = acc[i][j] + bias;
            if (c < 256) {
                int h = c >> 5, d = c & 31;
                qb[((size_t)(b * N_HEADS + h) * NN + nrow) * HEAD_DIM + d] = v;
            } else if (c < 512) {
                int cc = c - 256; int h = cc >> 5, d = cc & 31;
                kb[((size_t)(b * N_HEADS + h) * NN + nrow) * HEAD_DIM + d] = v;
            } else if (c < 768) {
                int cc = c - 512; int h = cc >> 5, d = cc & 31;
                vb[((size_t)(b * N_HEADS + h) * NN + nrow) * HEAD_DIM + d] = v;
            } else {
                taub[(size_t)(b * N_HEADS + (c - 768)) * NN + nrow] = v;
            }
        }
    }
}

// ---------------------------------------------------------------------------
// K3: fused attention. One block = (b, h, 16 q-rows). 256 threads =
// 16 rows x 16 col-groups. Scores (64/thread) in registers; full-row
// softmax via 16-lane shuffle reduce; K/V tiles staged in LDS (pad 33
// -> worst 2-way bank aliasing, free per m136).
// ---------------------------------------------------------------------------
__global__ __launch_bounds__(256)
void attn_kernel(const float* __restrict__ qb, const float* __restrict__ kb,
                 const float* __restrict__ vb, const float* __restrict__ taub,
                 const float* __restrict__ dist, float* __restrict__ ctx) {
    const int it = blockIdx.x;        // 0..63 (row tile)
    const int bh = blockIdx.y;        // 0..31
    const int b = bh >> 3, h = bh & 7;
    const int tj = threadIdx.x & 15;  // column group
    const int il = threadIdx.x >> 4;  // local row 0..15
    const int i = it * 16 + il;

    __shared__ float Qs[16][33];
    __shared__ float KVs[64][33];
    __shared__ float tau_s[16];

    if (threadIdx.x < 128) {
        int r = threadIdx.x >> 3, d4 = (threadIdx.x & 7) * 4;
        float4 qv = *(const float4*)&qb[((size_t)bh * NN + it * 16 + r) * HEAD_DIM + d4];
        Qs[r][d4+0] = qv.x; Qs[r][d4+1] = qv.y; Qs[r][d4+2] = qv.z; Qs[r][d4+3] = qv.w;
    }
    if (threadIdx.x < 16)
        tau_s[threadIdx.x] = taub[(size_t)bh * NN + it * 16 + threadIdx.x];

    float sc[64];
    const float scale = 0.17677669529663687f;  // 1/sqrt(32)
    const float* distrow = &dist[((size_t)b * NN + i) * NN];

    // ---- pass 1: scores ----
    #pragma unroll
    for (int jt = 0; jt < 16; jt++) {
        const int j0 = jt * 64;
        __syncthreads();  // guard KVs reuse (and Qs/tau_s on first iter)
        #pragma unroll
        for (int rep = 0; rep < 2; rep++) {
            int idx = rep * 256 + threadIdx.x;
            int jr = idx >> 3, d4 = (idx & 7) * 4;
            float4 kv = *(const float4*)&kb[((size_t)bh * NN + j0 + jr) * HEAD_DIM + d4];
            KVs[jr][d4+0] = kv.x; KVs[jr][d4+1] = kv.y; KVs[jr][d4+2] = kv.z; KVs[jr][d4+3] = kv.w;
        }
        __syncthreads();

        float4 dv = *(const float4*)&distrow[j0 + tj * 4];
        const float taui = tau_s[il];
        #pragma unroll
        for (int jj = 0; jj < 4; jj++) {
            const int jl = tj * 4 + jj;
            float s = 0.f;
            #pragma unroll
            for (int d = 0; d < 32; d++) s += Qs[il][d] * KVs[jl][d];
            const float dd = (jj == 0) ? dv.x : (jj == 1) ? dv.y : (jj == 2) ? dv.z : dv.w;
            sc[jt * 4 + jj] = s * scale + dd * taui;
        }
    }

    // ---- softmax across the row (64 regs x 16 lanes) ----
    float mx = -1e30f;
    #pragma unroll
    for (int x = 0; x < 64; x++) mx = fmaxf(mx, sc[x]);
    for (int mask = 1; mask < 16; mask <<= 1) mx = fmaxf(mx, __shfl_xor(mx, mask, 16));
    float l = 0.f;
    #pragma unroll
    for (int x = 0; x < 64; x++) { sc[x] = __expf(sc[x] - mx); l += sc[x]; }
    for (int mask = 1; mask < 16; mask <<= 1) l += __shfl_xor(l, mask, 16);
    const float inv = 1.0f / l;

    // ---- pass 2: ctx = P @ V ----
    float acc[HEAD_DIM] = {};
    #pragma unroll
    for (int jt = 0; jt < 16; jt++) {
        const int j0 = jt * 64;
        __syncthreads();
        #pragma unroll
        for (int rep = 0; rep < 2; rep++) {
            int idx = rep * 256 + threadIdx.x;
            int jr = idx >> 3, d4 = (idx & 7) * 4;
            float4 vv = *(const float4*)&vb[((size_t)bh * NN + j0 + jr) * HEAD_DIM + d4];
            KVs[jr][d4+0] = vv.x; KVs[jr][d4+1] = vv.y; KVs[jr][d4+2] = vv.z; KVs[jr][d4+3] = vv.w;
        }
        __syncthreads();
        #pragma unroll
        for (int jj = 0; jj < 4; jj++) {
            const float p = sc[jt * 4 + jj];
            const int jl = tj * 4 + jj;
            #pragma unroll
            for (int d = 0; d < 32; d++) acc[d] += p * KVs[jl][d];
        }
    }

    // reduce partial ctx across the 16 lanes of this row
    for (int mask = 1; mask < 16; mask <<= 1) {
        #pragma unroll
        for (int d = 0; d < 32; d++) acc[d] += __shfl_xor(acc[d], mask, 16);
    }
    // every lane now has the full sum; lane tj stores d = 2*tj, 2*tj+1
    float2 o = make_float2(acc[2 * tj] * inv, acc[2 * tj + 1] * inv);
    *(float2*)&ctx[((size_t)(b * NN + i)) * D_MODEL + h * HEAD_DIM + 2 * tj] = o;
}

// ---------------------------------------------------------------------------
// K4/K6/K7: generic tiled GEMM  C[m,n] = act(A[m,:] . W[n,:] + bias[n] (+res))
// A: (M x K) row-major, W: (N x K) row-major (i.e. computes A @ W^T).
// ---------------------------------------------------------------------------
template <bool RELU, bool ADDRES>
__global__ __launch_bounds__(256)
void gemm_kernel(const float* __restrict__ A, const float* __restrict__ W,
                 const float* __restrict__ bias, const float* __restrict__ res,
                 float* __restrict__ C, int N, int K) {
    __shared__ float As[16][65];
    __shared__ float Bs[16][65];
    const int n0 = blockIdx.x * 64;
    const int m0 = blockIdx.y * 64;
    const int lrow = threadIdx.x >> 2;
    const int kq   = threadIdx.x & 3;
    const int tx = threadIdx.x & 15, ty = threadIdx.x >> 4;

    float acc[4][4] = {};
    for (int k0 = 0; k0 < K; k0 += 16) {
        float4 av = *(const float4*)&A[(size_t)(m0 + lrow) * K + k0 + kq * 4];
        As[kq*4+0][lrow] = av.x; As[kq*4+1][lrow] = av.y;
        As[kq*4+2][lrow] = av.z; As[kq*4+3][lrow] = av.w;
        float4 bv = make_float4(0.f, 0.f, 0.f, 0.f);
        if (n0 + lrow < N) bv = *(const float4*)&W[(size_t)(n0 + lrow) * K + k0 + kq * 4];
        Bs[kq*4+0][lrow] = bv.x; Bs[kq*4+1][lrow] = bv.y;
        Bs[kq*4+2][lrow] = bv.z; Bs[kq*4+3][lrow] = bv.w;
        __syncthreads();

        #pragma unroll
        for (int k = 0; k < 16; k++) {
            float a0 = As[k][ty*4+0], a1 = As[k][ty*4+1], a2 = As[k][ty*4+2], a3 = As[k][ty*4+3];
            float b0 = Bs[k][tx*4+0], b1 = Bs[k][tx*4+1], b2 = Bs[k][tx*4+2], b3 = Bs[k][tx*4+3];
            acc[0][0] += a0*b0; acc[0][1] += a0*b1; acc[0][2] += a0*b2; acc[0][3] += a0*b3;
            acc[1][0] += a1*b0; acc[1][1] += a1*b1; acc[1][2] += a1*b2; acc[1][3] += a1*b3;
            acc[2][0] += a2*b0; acc[2][1] += a2*b1; acc[2][2] += a2*b2; acc[2][3] += a2*b3;
            acc[3][0] += a3*b0; acc[3][1] += a3*b1; acc[3][2] += a3*b2; acc[3][3] += a3*b3;
        }
        __syncthreads();
    }

    #pragma unroll
    for (int i = 0; i < 4; i++) {
        const int m = m0 + ty * 4 + i;
        #pragma unroll
        for (int j = 0; j < 4; j++) {
            const int n = n0 + tx * 4 + j;
            if (n < N) {
                float v = acc[i][j] + bias[n];
                if (RELU) v = fmaxf(v, 0.f);
                if (ADDRES) v += res[(size_t)m * N + n];
                C[(size_t)m * N + n] = v;
            }
        }
    }
}

// ---------------------------------------------------------------------------
// K5/K8: LayerNorm over rows of 256. One block per row, one thread per col.
// ---------------------------------------------------------------------------
__global__ __launch_bounds__(256)
void ln_kernel(const float* __restrict__ y, const float* __restrict__ g,
               const float* __restrict__ beta, float* __restrict__ o) {
    const int row = blockIdx.x;
    const float v = y[(size_t)row * D_MODEL + threadIdx.x];
    float s = v, sq = v * v;
    #pragma unroll
    for (int mask = 1; mask < 64; mask <<= 1) {
        s  += __shfl_xor(s, mask, 64);
        sq += __shfl_xor(sq, mask, 64);
    }
    __shared__ float rs_[4], rq_[4];
    const int w = threadIdx.x >> 6;
    if ((threadIdx.x & 63) == 0) { rs_[w] = s; rq_[w] = sq; }
    __syncthreads();
    s  = rs_[0] + rs_[1] + rs_[2] + rs_[3];
    sq = rq_[0] + rq_[1] + rq_[2] + rq_[3];
    const float mu = s * (1.0f / D_MODEL);
    const float var = sq * (1.0f / D_MODEL) - mu * mu;
    const float rstd = rsqrtf(var + LN_EPS);
    o[(size_t)row * D_MODEL + threadIdx.x] = (v - mu) * rstd * g[threadIdx.x] + beta[threadIdx.x];
}

// ---------------------------------------------------------------------------
// launch
// ---------------------------------------------------------------------------
extern "C" void kernel_launch(void* const* d_in, const int* in_sizes, int n_in,
                              void* d_out, int out_size, void* d_ws, size_t ws_size,
                              hipStream_t stream) {
    const float* embed     = (const float*)d_in[0];
    // d_in[1] refer_bbox: unused by the reference
    const float* dist      = (const float*)d_in[2];
    const float* query_pos = (const float*)d_in[3];
    const float* in_proj_w = (const float*)d_in[4];
    const float* in_proj_b = (const float*)d_in[5];
    const float* out_w     = (const float*)d_in[6];
    const float* out_b     = (const float*)d_in[7];
    const float* tau_w     = (const float*)d_in[8];
    const float* tau_b     = (const float*)d_in[9];
    const float* w1        = (const float*)d_in[10];
    const float* b1        = (const float*)d_in[11];
    const float* w2        = (const float*)d_in[12];
    const float* b2        = (const float*)d_in[13];
    const float* g1        = (const float*)d_in[14];
    const float* beta1     = (const float*)d_in[15];
    const float* g2        = (const float*)d_in[16];
    const float* beta2     = (const float*)d_in[17];
    float* out = (float*)d_out;

    char* ws = (char*)d_ws;
    const size_t SZ_MAT = (size_t)M_TOT * D_MODEL * 4;       // 4 MB
    float* qk_in = (float*)(ws);
    float* qb    = (float*)(ws + SZ_MAT);
    float* kb    = (float*)(ws + 2 * SZ_MAT);
    float* vb    = (float*)(ws + 3 * SZ_MAT);
    float* taub  = (float*)(ws + 4 * SZ_MAT);                 // 128 KB
    float* ctx   = (float*)(ws + 4 * SZ_MAT + 131072);
    float* y1    = (float*)(ws + 5 * SZ_MAT + 131072);
    float* x     = (float*)(ws + 6 * SZ_MAT + 131072);
    float* ffn   = (float*)(ws + 7 * SZ_MAT + 131072);        // 16 MB
    float* y2    = (float*)(ws + 11 * SZ_MAT + 131072);

    // K1: qk_in = embed + query_pos
    add_kernel<<<dim3((M_TOT * D_MODEL / 4 + 255) / 256), dim3(256), 0, stream>>>(
        embed, query_pos, qk_in, M_TOT * D_MODEL / 4);

    // K2: q,k,v,tau projection
    qkv_kernel<<<dim3(13, M_TOT / 64), dim3(256), 0, stream>>>(
        qk_in, embed, in_proj_w, in_proj_b, tau_w, tau_b, qb, kb, vb, taub);

    // K3: fused attention -> ctx (B,N,D_MODEL)
    attn_kernel<<<dim3(NN / 16, BB * N_HEADS), dim3(256), 0, stream>>>(
        qb, kb, vb, taub, dist, ctx);

    // K4: y1 = ctx @ out_w^T + out_b + embed
    gemm_kernel<false, true><<<dim3(D_MODEL / 64, M_TOT / 64), dim3(256), 0, stream>>>(
        ctx, out_w, out_b, embed, y1, D_MODEL, D_MODEL);

    // K5: x = LN(y1)
    ln_kernel<<<dim3(M_TOT), dim3(256), 0, stream>>>(y1, g1, beta1, x);

    // K6: ffn = relu(x @ w1^T + b1)
    gemm_kernel<true, false><<<dim3(D_FFN / 64, M_TOT / 64), dim3(256), 0, stream>>>(
        x, w1, b1, nullptr, ffn, D_FFN, D_MODEL);

    // K7: y2 = ffn @ w2^T + b2 + x
    gemm_kernel<false, true><<<dim3(D_MODEL / 64, M_TOT / 64), dim3(256), 0, stream>>>(
        ffn, w2, b2, x, y2, D_MODEL, D_FFN);

    // K8: out = LN(y2)
    ln_kernel<<<dim3(M_TOT), dim3(256), 0, stream>>>(y2, g2, beta2, out);
}

// Round 2
// 386.670 us; speedup vs baseline: 2.2033x; 2.2033x over previous
//
#include <hip/hip_runtime.h>
#include <math.h>

#define D_MODEL 256
#define N_HEADS 8
#define HEAD_DIM 32
#define D_FFN   1024
#define BB      4
#define NN      1024
#define M_TOT   (BB * NN)     // 4096 rows
#define LN_EPS  1e-5f

typedef float f32x4 __attribute__((ext_vector_type(4)));
typedef short bf16x8 __attribute__((ext_vector_type(8)));

__device__ __forceinline__ unsigned short f2bf(float f) {
    unsigned int u = __float_as_uint(f);
    unsigned int r = (u + 0x7fffu + ((u >> 16) & 1u)) >> 16;
    return (unsigned short)r;
}

// ---------------------------------------------------------------------------
// K1: qk_in = embed + query_pos (elementwise, float4)
// ---------------------------------------------------------------------------
__global__ __launch_bounds__(256)
void add_kernel(const float* __restrict__ a, const float* __restrict__ b,
                float* __restrict__ o, int n4) {
    int i = blockIdx.x * blockDim.x + threadIdx.x;
    if (i < n4) {
        float4 x = ((const float4*)a)[i];
        float4 y = ((const float4*)b)[i];
        x.x += y.x; x.y += y.y; x.z += y.z; x.w += y.w;
        ((float4*)o)[i] = x;
    }
}

// ---------------------------------------------------------------------------
// K2: fused qkv + tau projection (fp32 compute, bf16 q/k/v outputs).
//   cols [0,256)  : q -> qb[bh][n][32]  bf16
//   cols [256,512): k -> kb[bh][n][32]  bf16
//   cols [512,768): v -> vbT[bh][32][n] bf16 (transposed for PV B-frags)
//   cols [768,776): tau -> taub[bh][n]  fp32
// ---------------------------------------------------------------------------
__global__ __launch_bounds__(256)
void qkv_kernel(const float* __restrict__ qk_in, const float* __restrict__ embed,
                const float* __restrict__ in_proj_w, const float* __restrict__ in_proj_b,
                const float* __restrict__ tau_w, const float* __restrict__ tau_b,
                unsigned short* __restrict__ qb, unsigned short* __restrict__ kb,
                unsigned short* __restrict__ vbT, float* __restrict__ taub) {
    __shared__ float As[16][65];
    __shared__ float Bs[16][65];
    const int K = D_MODEL;
    const int n0 = blockIdx.x * 64;
    const int m0 = blockIdx.y * 64;
    const float* A = (blockIdx.x < 8) ? qk_in : embed;  // q,k tiles use embed+pos

    const int lrow = threadIdx.x >> 2;   // 0..63
    const int kq   = threadIdx.x & 3;    // 0..3
    const int tx = threadIdx.x & 15, ty = threadIdx.x >> 4;

    float acc[4][4] = {};
    for (int k0 = 0; k0 < K; k0 += 16) {
        float4 av = *(const float4*)&A[(size_t)(m0 + lrow) * K + k0 + kq * 4];
        As[kq*4+0][lrow] = av.x; As[kq*4+1][lrow] = av.y;
        As[kq*4+2][lrow] = av.z; As[kq*4+3][lrow] = av.w;

        const int c = n0 + lrow;
        float4 bv = make_float4(0.f, 0.f, 0.f, 0.f);
        if (c < 768)      bv = *(const float4*)&in_proj_w[(size_t)c * K + k0 + kq * 4];
        else if (c < 776) bv = *(const float4*)&tau_w[(size_t)(c - 768) * K + k0 + kq * 4];
        Bs[kq*4+0][lrow] = bv.x; Bs[kq*4+1][lrow] = bv.y;
        Bs[kq*4+2][lrow] = bv.z; Bs[kq*4+3][lrow] = bv.w;
        __syncthreads();

        #pragma unroll
        for (int k = 0; k < 16; k++) {
            float a0 = As[k][ty*4+0], a1 = As[k][ty*4+1], a2 = As[k][ty*4+2], a3 = As[k][ty*4+3];
            float b0 = Bs[k][tx*4+0], b1 = Bs[k][tx*4+1], b2 = Bs[k][tx*4+2], b3 = Bs[k][tx*4+3];
            acc[0][0] += a0*b0; acc[0][1] += a0*b1; acc[0][2] += a0*b2; acc[0][3] += a0*b3;
            acc[1][0] += a1*b0; acc[1][1] += a1*b1; acc[1][2] += a1*b2; acc[1][3] += a1*b3;
            acc[2][0] += a2*b0; acc[2][1] += a2*b1; acc[2][2] += a2*b2; acc[2][3] += a2*b3;
            acc[3][0] += a3*b0; acc[3][1] += a3*b1; acc[3][2] += a3*b2; acc[3][3] += a3*b3;
        }
        __syncthreads();
    }

    #pragma unroll
    for (int i = 0; i < 4; i++) {
        const int m = m0 + ty * 4 + i;
        const int b = m >> 10;          // / NN
        const int nrow = m & 1023;      // % NN
        #pragma unroll
        for (int j = 0; j < 4; j++) {
            const int c = n0 + tx * 4 + j;
            if (c >= 776) continue;
            const float bias = (c < 768) ? in_proj_b[c] : tau_b[c - 768];
            const float v = acc[i][j] + bias;
            if (c < 256) {
                int h = c >> 5, d = c & 31;
                qb[((size_t)(b * N_HEADS + h) * NN + nrow) * HEAD_DIM + d] = f2bf(v);
            } else if (c < 512) {
                int cc = c - 256; int h = cc >> 5, d = cc & 31;
                kb[((size_t)(b * N_HEADS + h) * NN + nrow) * HEAD_DIM + d] = f2bf(v);
            } else if (c < 768) {
                int cc = c - 512; int h = cc >> 5, d = cc & 31;
                vbT[((size_t)(b * N_HEADS + h) * HEAD_DIM + d) * NN + nrow] = f2bf(v);
            } else {
                taub[(size_t)(b * N_HEADS + (c - 768)) * NN + nrow] = v;
            }
        }
    }
}

// ---------------------------------------------------------------------------
// K3: flash-style MFMA attention. Block = 4 waves; wave owns 16 Q rows of
// one (b,h). Per 64-key tile: 4 QK^T MFMAs (16x16x32 bf16, K=HEAD_DIM),
// bias = dist*tau, online softmax (16-lane shuffle reduces within each
// C-layout quad), P C->A layout via per-wave LDS tile (stride 72 bf16 ->
// <=2-way bank aliasing), PV via 4 MFMAs against pre-transposed V.
// ---------------------------------------------------------------------------
__global__ __launch_bounds__(256)
void attn_mfma_kernel(const unsigned short* __restrict__ qb,
                      const unsigned short* __restrict__ kb,
                      const unsigned short* __restrict__ vbT,
                      const float* __restrict__ taub,
                      const float* __restrict__ dist,
                      float* __restrict__ ctx) {
    __shared__ unsigned short Plds[4][16 * 72];   // per-wave P tile (16x64, pad 72)
    const int w    = threadIdx.x >> 6;
    const int lane = threadIdx.x & 63;
    const int l16  = lane & 15;      // A:m / B:n / C:col
    const int l4   = lane >> 4;      // quad
    const int bh = blockIdx.y;
    const int b = bh >> 3, h = bh & 7;
    const int i0 = blockIdx.x * 64 + w * 16;

    const f32x4 zero = {0.f, 0.f, 0.f, 0.f};
    // Q A-frag: A[m=l16][k=l4*8+j]
    bf16x8 qf = *(const bf16x8*)&qb[((size_t)bh * NN + i0 + l16) * HEAD_DIM + l4 * 8];

    float tau_r[4];
    #pragma unroll
    for (int r = 0; r < 4; r++)
        tau_r[r] = taub[(size_t)bh * NN + i0 + l4 * 4 + r];

    float m_r[4], l_r[4];
    f32x4 O0 = zero, O1 = zero;
    #pragma unroll
    for (int r = 0; r < 4; r++) { m_r[r] = -1e30f; l_r[r] = 0.f; }

    const float scale = 0.17677669529663687f;  // 1/sqrt(32)
    unsigned short* pw = &Plds[w][0];

    for (int kt = 0; kt < 16; kt++) {
        const int j0 = kt * 64;
        float sarr[4][4];
        #pragma unroll
        for (int s = 0; s < 4; s++) {
            const int js = j0 + s * 16;
            // K B-frag: B[k=d][n=j] <- kb row (js+l16), 8 consecutive d
            bf16x8 kf = *(const bf16x8*)&kb[((size_t)bh * NN + js + l16) * HEAD_DIM + l4 * 8];
            f32x4 S = __builtin_amdgcn_mfma_f32_16x16x32_bf16(qf, kf, zero, 0, 0, 0);
            #pragma unroll
            for (int r = 0; r < 4; r++) {
                const int i = i0 + l4 * 4 + r;
                const float dd = dist[((size_t)b * NN + i) * NN + js + l16];
                sarr[s][r] = S[r] * scale + dd * tau_r[r];
            }
        }
        // ---- online softmax per row r (row lives in 16 lanes of this quad) ----
        #pragma unroll
        for (int r = 0; r < 4; r++) {
            float mx = fmaxf(fmaxf(sarr[0][r], sarr[1][r]), fmaxf(sarr[2][r], sarr[3][r]));
            #pragma unroll
            for (int msk = 1; msk < 16; msk <<= 1) mx = fmaxf(mx, __shfl_xor(mx, msk, 16));
            const float mnew = fmaxf(m_r[r], mx);
            const float alpha = __expf(m_r[r] - mnew);
            m_r[r] = mnew;
            float ps = 0.f;
            #pragma unroll
            for (int s = 0; s < 4; s++) {
                const float p = __expf(sarr[s][r] - mnew);
                sarr[s][r] = p; ps += p;
            }
            #pragma unroll
            for (int msk = 1; msk < 16; msk <<= 1) ps += __shfl_xor(ps, msk, 16);
            l_r[r] = l_r[r] * alpha + ps;
            O0[r] *= alpha; O1[r] *= alpha;
        }
        // ---- P: C-layout -> A-layout via wave-private LDS ----
        #pragma unroll
        for (int s = 0; s < 4; s++)
            #pragma unroll
            for (int r = 0; r < 4; r++)
                pw[(l4 * 4 + r) * 72 + s * 16 + l16] = f2bf(sarr[s][r]);
        asm volatile("s_waitcnt lgkmcnt(0)" ::: "memory");  // wave-local RAW drain
        #pragma unroll
        for (int c = 0; c < 2; c++) {
            bf16x8 pf = *(const bf16x8*)&pw[l16 * 72 + c * 32 + l4 * 8];
            // V B-frags: B[k=j][n=d] <- vbT row d, 8 consecutive j
            bf16x8 v0 = *(const bf16x8*)&vbT[((size_t)bh * HEAD_DIM + l16) * NN + j0 + c * 32 + l4 * 8];
            bf16x8 v1 = *(const bf16x8*)&vbT[((size_t)bh * HEAD_DIM + 16 + l16) * NN + j0 + c * 32 + l4 * 8];
            O0 = __builtin_amdgcn_mfma_f32_16x16x32_bf16(pf, v0, O0, 0, 0, 0);
            O1 = __builtin_amdgcn_mfma_f32_16x16x32_bf16(pf, v1, O1, 0, 0, 0);
        }
    }
    // ---- epilogue: ctx[b][i][h*32 + d] = O / l ----
    #pragma unroll
    for (int r = 0; r < 4; r++) {
        const float inv = 1.0f / l_r[r];
        const int i = i0 + l4 * 4 + r;
        float* crow = &ctx[((size_t)b * NN + i) * D_MODEL + h * HEAD_DIM];
        crow[l16]      = O0[r] * inv;
        crow[16 + l16] = O1[r] * inv;
    }
}

// ---------------------------------------------------------------------------
// K4/K6/K7: generic tiled GEMM  C[m,n] = act(A[m,:] . W[n,:] + bias[n] (+res))
// ---------------------------------------------------------------------------
template <bool RELU, bool ADDRES>
__global__ __launch_bounds__(256)
void gemm_kernel(const float* __restrict__ A, const float* __restrict__ W,
                 const float* __restrict__ bias, const float* __restrict__ res,
                 float* __restrict__ C, int N, int K) {
    __shared__ float As[16][65];
    __shared__ float Bs[16][65];
    const int n0 = blockIdx.x * 64;
    const int m0 = blockIdx.y * 64;
    const int lrow = threadIdx.x >> 2;
    const int kq   = threadIdx.x & 3;
    const int tx = threadIdx.x & 15, ty = threadIdx.x >> 4;

    float acc[4][4] = {};
    for (int k0 = 0; k0 < K; k0 += 16) {
        float4 av = *(const float4*)&A[(size_t)(m0 + lrow) * K + k0 + kq * 4];
        As[kq*4+0][lrow] = av.x; As[kq*4+1][lrow] = av.y;
        As[kq*4+2][lrow] = av.z; As[kq*4+3][lrow] = av.w;
        float4 bv = make_float4(0.f, 0.f, 0.f, 0.f);
        if (n0 + lrow < N) bv = *(const float4*)&W[(size_t)(n0 + lrow) * K + k0 + kq * 4];
        Bs[kq*4+0][lrow] = bv.x; Bs[kq*4+1][lrow] = bv.y;
        Bs[kq*4+2][lrow] = bv.z; Bs[kq*4+3][lrow] = bv.w;
        __syncthreads();

        #pragma unroll
        for (int k = 0; k < 16; k++) {
            float a0 = As[k][ty*4+0], a1 = As[k][ty*4+1], a2 = As[k][ty*4+2], a3 = As[k][ty*4+3];
            float b0 = Bs[k][tx*4+0], b1 = Bs[k][tx*4+1], b2 = Bs[k][tx*4+2], b3 = Bs[k][tx*4+3];
            acc[0][0] += a0*b0; acc[0][1] += a0*b1; acc[0][2] += a0*b2; acc[0][3] += a0*b3;
            acc[1][0] += a1*b0; acc[1][1] += a1*b1; acc[1][2] += a1*b2; acc[1][3] += a1*b3;
            acc[2][0] += a2*b0; acc[2][1] += a2*b1; acc[2][2] += a2*b2; acc[2][3] += a2*b3;
            acc[3][0] += a3*b0; acc[3][1] += a3*b1; acc[3][2] += a3*b2; acc[3][3] += a3*b3;
        }
        __syncthreads();
    }

    #pragma unroll
    for (int i = 0; i < 4; i++) {
        const int m = m0 + ty * 4 + i;
        #pragma unroll
        for (int j = 0; j < 4; j++) {
            const int n = n0 + tx * 4 + j;
            if (n < N) {
                float v = acc[i][j] + bias[n];
                if (RELU) v = fmaxf(v, 0.f);
                if (ADDRES) v += res[(size_t)m * N + n];
                C[(size_t)m * N + n] = v;
            }
        }
    }
}

// ---------------------------------------------------------------------------
// K5/K8: LayerNorm over rows of 256.
// ---------------------------------------------------------------------------
__global__ __launch_bounds__(256)
void ln_kernel(const float* __restrict__ y, const float* __restrict__ g,
               const float* __restrict__ beta, float* __restrict__ o) {
    const int row = blockIdx.x;
    const float v = y[(size_t)row * D_MODEL + threadIdx.x];
    float s = v, sq = v * v;
    #pragma unroll
    for (int mask = 1; mask < 64; mask <<= 1) {
        s  += __shfl_xor(s, mask, 64);
        sq += __shfl_xor(sq, mask, 64);
    }
    __shared__ float rs_[4], rq_[4];
    const int w = threadIdx.x >> 6;
    if ((threadIdx.x & 63) == 0) { rs_[w] = s; rq_[w] = sq; }
    __syncthreads();
    s  = rs_[0] + rs_[1] + rs_[2] + rs_[3];
    sq = rq_[0] + rq_[1] + rq_[2] + rq_[3];
    const float mu = s * (1.0f / D_MODEL);
    const float var = sq * (1.0f / D_MODEL) - mu * mu;
    const float rstd = rsqrtf(var + LN_EPS);
    o[(size_t)row * D_MODEL + threadIdx.x] = (v - mu) * rstd * g[threadIdx.x] + beta[threadIdx.x];
}

// ---------------------------------------------------------------------------
// launch
// ---------------------------------------------------------------------------
extern "C" void kernel_launch(void* const* d_in, const int* in_sizes, int n_in,
                              void* d_out, int out_size, void* d_ws, size_t ws_size,
                              hipStream_t stream) {
    const float* embed     = (const float*)d_in[0];
    const float* dist      = (const float*)d_in[2];
    const float* query_pos = (const float*)d_in[3];
    const float* in_proj_w = (const float*)d_in[4];
    const float* in_proj_b = (const float*)d_in[5];
    const float* out_w     = (const float*)d_in[6];
    const float* out_b     = (const float*)d_in[7];
    const float* tau_w     = (const float*)d_in[8];
    const float* tau_b     = (const float*)d_in[9];
    const float* w1        = (const float*)d_in[10];
    const float* b1        = (const float*)d_in[11];
    const float* w2        = (const float*)d_in[12];
    const float* b2        = (const float*)d_in[13];
    const float* g1        = (const float*)d_in[14];
    const float* beta1     = (const float*)d_in[15];
    const float* g2        = (const float*)d_in[16];
    const float* beta2     = (const float*)d_in[17];
    float* out = (float*)d_out;

    char* ws = (char*)d_ws;
    const size_t MB = 1024 * 1024;
    float*          qk_in = (float*)(ws);                       // 4 MB fp32
    unsigned short* qb    = (unsigned short*)(ws + 4 * MB);     // 2 MB bf16
    unsigned short* kb    = (unsigned short*)(ws + 6 * MB);     // 2 MB bf16
    unsigned short* vbT   = (unsigned short*)(ws + 8 * MB);     // 2 MB bf16
    float*          taub  = (float*)(ws + 10 * MB);             // 128 KB fp32
    float*          ctx   = (float*)(ws + 11 * MB);             // 4 MB
    float*          y1    = (float*)(ws + 15 * MB);             // 4 MB
    float*          x     = (float*)(ws + 19 * MB);             // 4 MB
    float*          ffn   = (float*)(ws + 23 * MB);             // 16 MB
    float*          y2    = (float*)(ws + 39 * MB);             // 4 MB

    // K1: qk_in = embed + query_pos
    add_kernel<<<dim3((M_TOT * D_MODEL / 4 + 255) / 256), dim3(256), 0, stream>>>(
        embed, query_pos, qk_in, M_TOT * D_MODEL / 4);

    // K2: q,k,v,tau projection (bf16 outputs)
    qkv_kernel<<<dim3(13, M_TOT / 64), dim3(256), 0, stream>>>(
        qk_in, embed, in_proj_w, in_proj_b, tau_w, tau_b, qb, kb, vbT, taub);

    // K3: flash MFMA attention -> ctx (B,N,D_MODEL) fp32
    attn_mfma_kernel<<<dim3(NN / 64, BB * N_HEADS), dim3(256), 0, stream>>>(
        qb, kb, vbT, taub, dist, ctx);

    // K4: y1 = ctx @ out_w^T + out_b + embed
    gemm_kernel<false, true><<<dim3(D_MODEL / 64, M_TOT / 64), dim3(256), 0, stream>>>(
        ctx, out_w, out_b, embed, y1, D_MODEL, D_MODEL);

    // K5: x = LN(y1)
    ln_kernel<<<dim3(M_TOT), dim3(256), 0, stream>>>(y1, g1, beta1, x);

    // K6: ffn = relu(x @ w1^T + b1)
    gemm_kernel<true, false><<<dim3(D_FFN / 64, M_TOT / 64), dim3(256), 0, stream>>>(
        x, w1, b1, nullptr, ffn, D_FFN, D_MODEL);

    // K7: y2 = ffn @ w2^T + b2 + x
    gemm_kernel<false, true><<<dim3(D_MODEL / 64, M_TOT / 64), dim3(256), 0, stream>>>(
        ffn, w2, b2, x, y2, D_MODEL, D_FFN);

    // K8: out = LN(y2)
    ln_kernel<<<dim3(M_TOT), dim3(256), 0, stream>>>(y2, g2, beta2, out);
}

// Round 3
// 213.637 us; speedup vs baseline: 3.9878x; 1.8099x over previous
//
#include <hip/hip_runtime.h>
#include <math.h>

#define D_MODEL 256
#define N_HEADS 8
#define HEAD_DIM 32
#define D_FFN   1024
#define BB      4
#define NN      1024
#define M_TOT   (BB * NN)     // 4096 rows
#define LN_EPS  1e-5f

typedef float f32x4 __attribute__((ext_vector_type(4)));
typedef short bf16x8 __attribute__((ext_vector_type(8)));

__device__ __forceinline__ unsigned short f2bf(float f) {
    unsigned int u = __float_as_uint(f);
    unsigned int r = (u + 0x7fffu + ((u >> 16) & 1u)) >> 16;
    return (unsigned short)r;
}
__device__ __forceinline__ ushort4 pack4(float4 v) {
    ushort4 o; o.x = f2bf(v.x); o.y = f2bf(v.y); o.z = f2bf(v.z); o.w = f2bf(v.w);
    return o;
}

// ---------------------------------------------------------------------------
// K1: emb_bf = bf16(embed); qk_bf = bf16(embed + query_pos)
// ---------------------------------------------------------------------------
__global__ __launch_bounds__(256)
void prep_kernel(const float4* __restrict__ e, const float4* __restrict__ qp,
                 ushort4* __restrict__ ebf, ushort4* __restrict__ qkbf, int n4) {
    int i = blockIdx.x * blockDim.x + threadIdx.x;
    if (i < n4) {
        float4 ev = e[i], pv = qp[i];
        ebf[i] = pack4(ev);
        float4 s = make_float4(ev.x + pv.x, ev.y + pv.y, ev.z + pv.z, ev.w + pv.w);
        qkbf[i] = pack4(s);
    }
}

// ---------------------------------------------------------------------------
// K2: convert all weights fp32 -> bf16 (one launch). tau_w lands in a
// zero-padded 64x256 tile so qkv GEMM's 13th n-block can consume it.
// Ranges in float4 units: inw 49152 | outw 16384 | w1 65536 | w2 65536 | taupad 4096
// ---------------------------------------------------------------------------
__global__ __launch_bounds__(256)
void cvt_w_kernel(const float4* __restrict__ inw, const float4* __restrict__ outw,
                  const float4* __restrict__ w1, const float4* __restrict__ w2,
                  const float4* __restrict__ tauw,
                  ushort4* __restrict__ o_inw, ushort4* __restrict__ o_outw,
                  ushort4* __restrict__ o_w1, ushort4* __restrict__ o_w2,
                  ushort4* __restrict__ o_taupad) {
    int i = blockIdx.x * blockDim.x + threadIdx.x;
    if (i < 49152)       o_inw[i] = pack4(inw[i]);
    else if (i < 65536)  o_outw[i - 49152] = pack4(outw[i - 49152]);
    else if (i < 131072) o_w1[i - 65536] = pack4(w1[i - 65536]);
    else if (i < 196608) o_w2[i - 131072] = pack4(w2[i - 131072]);
    else if (i < 200704) {
        int q = i - 196608;                       // 0..4095 (64 rows x 64 quads)
        if (q < 512) o_taupad[q] = pack4(tauw[q]);  // first 8 rows = tau_w
        else { ushort4 z = {0, 0, 0, 0}; o_taupad[q] = z; }
    }
}

// ---------------------------------------------------------------------------
// K3: qkv+tau as register-direct MFMA GEMM. Block = 64x64 tile, 4 waves 2x2,
// each wave 32x32 via 2x2 of 16x16x32 bf16 MFMAs, K=256 fully unrolled.
// n-blocks 0-7: q,k (A = qk_bf); 8-11: v (A = emb_bf); 12: tau (W = taupad).
// Epilogue scatters to qb/kb (row-major bf16), vbT (transposed bf16), taub (f32).
// ---------------------------------------------------------------------------
__global__ __launch_bounds__(256)
void qkv_mfma_kernel(const unsigned short* __restrict__ qk_bf,
                     const unsigned short* __restrict__ emb_bf,
                     const unsigned short* __restrict__ inw_bf,
                     const unsigned short* __restrict__ taupad,
                     const float* __restrict__ in_proj_b, const float* __restrict__ tau_b,
                     unsigned short* __restrict__ qb, unsigned short* __restrict__ kb,
                     unsigned short* __restrict__ vbT, float* __restrict__ taub) {
    const int w    = threadIdx.x >> 6;
    const int lane = threadIdx.x & 63;
    const int l16 = lane & 15, l4 = lane >> 4;
    const int n0 = blockIdx.x * 64;
    const int m0 = blockIdx.y * 64;
    const int wm = (w >> 1) * 32, wn = (w & 1) * 32;

    const unsigned short* A = (blockIdx.x < 8) ? qk_bf : emb_bf;
    const unsigned short* W0 = (n0 < 768) ? &inw_bf[(size_t)(n0 + wn + l16) * D_MODEL]
                                          : &taupad[(size_t)(wn + l16) * D_MODEL];
    const unsigned short* Ar0 = &A[(size_t)(m0 + wm + l16) * D_MODEL];

    f32x4 acc[2][2] = {};
    #pragma unroll
    for (int k0 = 0; k0 < D_MODEL; k0 += 32) {
        bf16x8 a0 = *(const bf16x8*)&Ar0[k0 + l4 * 8];
        bf16x8 a1 = *(const bf16x8*)&Ar0[16 * D_MODEL + k0 + l4 * 8];
        bf16x8 b0 = *(const bf16x8*)&W0[k0 + l4 * 8];
        bf16x8 b1 = *(const bf16x8*)&W0[16 * D_MODEL + k0 + l4 * 8];
        acc[0][0] = __builtin_amdgcn_mfma_f32_16x16x32_bf16(a0, b0, acc[0][0], 0, 0, 0);
        acc[0][1] = __builtin_amdgcn_mfma_f32_16x16x32_bf16(a0, b1, acc[0][1], 0, 0, 0);
        acc[1][0] = __builtin_amdgcn_mfma_f32_16x16x32_bf16(a1, b0, acc[1][0], 0, 0, 0);
        acc[1][1] = __builtin_amdgcn_mfma_f32_16x16x32_bf16(a1, b1, acc[1][1], 0, 0, 0);
    }

    #pragma unroll
    for (int i = 0; i < 2; i++) {
        #pragma unroll
        for (int j = 0; j < 2; j++) {
            #pragma unroll
            for (int r = 0; r < 4; r++) {
                const int m = m0 + wm + i * 16 + l4 * 4 + r;
                const int b = m >> 10, nrow = m & 1023;
                const int c = n0 + wn + j * 16 + l16;
                float v = acc[i][j][r];
                if (c < 256) {
                    v += in_proj_b[c];
                    int h = c >> 5, d = c & 31;
                    qb[((size_t)(b * N_HEADS + h) * NN + nrow) * HEAD_DIM + d] = f2bf(v);
                } else if (c < 512) {
                    v += in_proj_b[c];
                    int cc = c - 256; int h = cc >> 5, d = cc & 31;
                    kb[((size_t)(b * N_HEADS + h) * NN + nrow) * HEAD_DIM + d] = f2bf(v);
                } else if (c < 768) {
                    v += in_proj_b[c];
                    int cc = c - 512; int h = cc >> 5, d = cc & 31;
                    vbT[((size_t)(b * N_HEADS + h) * HEAD_DIM + d) * NN + nrow] = f2bf(v);
                } else if (c < 776) {
                    v += tau_b[c - 768];
                    taub[(size_t)(b * N_HEADS + (c - 768)) * NN + nrow] = v;
                }
            }
        }
    }
}

// ---------------------------------------------------------------------------
// K4: flash-style MFMA attention (as R1) with: hoisted K-frag + dist loads,
// ILP-batched softmax reductions (4 independent shuffle chains), bf16 ctx out.
// ---------------------------------------------------------------------------
__global__ __launch_bounds__(256)
void attn_mfma_kernel(const unsigned short* __restrict__ qb,
                      const unsigned short* __restrict__ kb,
                      const unsigned short* __restrict__ vbT,
                      const float* __restrict__ taub,
                      const float* __restrict__ dist,
                      unsigned short* __restrict__ ctx) {
    __shared__ unsigned short Plds[4][16 * 72];   // per-wave P tile (16x64, pad 72)
    const int w    = threadIdx.x >> 6;
    const int lane = threadIdx.x & 63;
    const int l16  = lane & 15;
    const int l4   = lane >> 4;
    const int bh = blockIdx.y;
    const int b = bh >> 3, h = bh & 7;
    const int i0 = blockIdx.x * 64 + w * 16;

    const f32x4 zero = {0.f, 0.f, 0.f, 0.f};
    bf16x8 qf = *(const bf16x8*)&qb[((size_t)bh * NN + i0 + l16) * HEAD_DIM + l4 * 8];

    float tau_r[4];
    const float* drow[4];
    #pragma unroll
    for (int r = 0; r < 4; r++) {
        tau_r[r] = taub[(size_t)bh * NN + i0 + l4 * 4 + r];
        drow[r] = &dist[((size_t)b * NN + i0 + l4 * 4 + r) * NN];
    }

    float m_r[4], l_r[4];
    f32x4 O0 = zero, O1 = zero;
    #pragma unroll
    for (int r = 0; r < 4; r++) { m_r[r] = -1e30f; l_r[r] = 0.f; }

    const float scale = 0.17677669529663687f;  // 1/sqrt(32)
    unsigned short* pw = &Plds[w][0];

    for (int kt = 0; kt < 16; kt++) {
        const int j0 = kt * 64;
        // ---- hoisted loads: 4 K-frags + 16 dist scalars ----
        bf16x8 kf[4];
        float dd[4][4];
        #pragma unroll
        for (int s = 0; s < 4; s++)
            kf[s] = *(const bf16x8*)&kb[((size_t)bh * NN + j0 + s * 16 + l16) * HEAD_DIM + l4 * 8];
        #pragma unroll
        for (int s = 0; s < 4; s++)
            #pragma unroll
            for (int r = 0; r < 4; r++)
                dd[s][r] = drow[r][j0 + s * 16 + l16];

        float sarr[4][4];
        #pragma unroll
        for (int s = 0; s < 4; s++) {
            f32x4 S = __builtin_amdgcn_mfma_f32_16x16x32_bf16(qf, kf[s], zero, 0, 0, 0);
            #pragma unroll
            for (int r = 0; r < 4; r++)
                sarr[s][r] = S[r] * scale + dd[s][r] * tau_r[r];
        }

        // ---- online softmax: 4 independent reduce chains (ILP) ----
        float mx[4], ps[4];
        #pragma unroll
        for (int r = 0; r < 4; r++)
            mx[r] = fmaxf(fmaxf(sarr[0][r], sarr[1][r]), fmaxf(sarr[2][r], sarr[3][r]));
        #pragma unroll
        for (int msk = 1; msk < 16; msk <<= 1)
            #pragma unroll
            for (int r = 0; r < 4; r++)
                mx[r] = fmaxf(mx[r], __shfl_xor(mx[r], msk, 16));
        float alpha[4];
        #pragma unroll
        for (int r = 0; r < 4; r++) {
            const float mnew = fmaxf(m_r[r], mx[r]);
            alpha[r] = __expf(m_r[r] - mnew);
            m_r[r] = mnew;
            ps[r] = 0.f;
        }
        #pragma unroll
        for (int s = 0; s < 4; s++)
            #pragma unroll
            for (int r = 0; r < 4; r++) {
                const float p = __expf(sarr[s][r] - m_r[r]);
                sarr[s][r] = p; ps[r] += p;
            }
        #pragma unroll
        for (int msk = 1; msk < 16; msk <<= 1)
            #pragma unroll
            for (int r = 0; r < 4; r++)
                ps[r] += __shfl_xor(ps[r], msk, 16);
        #pragma unroll
        for (int r = 0; r < 4; r++) {
            l_r[r] = l_r[r] * alpha[r] + ps[r];
            O0[r] *= alpha[r]; O1[r] *= alpha[r];
        }

        // ---- P: C-layout -> A-layout via wave-private LDS ----
        #pragma unroll
        for (int s = 0; s < 4; s++)
            #pragma unroll
            for (int r = 0; r < 4; r++)
                pw[(l4 * 4 + r) * 72 + s * 16 + l16] = f2bf(sarr[s][r]);
        asm volatile("s_waitcnt lgkmcnt(0)" ::: "memory");  // wave-local RAW drain
        #pragma unroll
        for (int c = 0; c < 2; c++) {
            bf16x8 pf = *(const bf16x8*)&pw[l16 * 72 + c * 32 + l4 * 8];
            bf16x8 v0 = *(const bf16x8*)&vbT[((size_t)bh * HEAD_DIM + l16) * NN + j0 + c * 32 + l4 * 8];
            bf16x8 v1 = *(const bf16x8*)&vbT[((size_t)bh * HEAD_DIM + 16 + l16) * NN + j0 + c * 32 + l4 * 8];
            O0 = __builtin_amdgcn_mfma_f32_16x16x32_bf16(pf, v0, O0, 0, 0, 0);
            O1 = __builtin_amdgcn_mfma_f32_16x16x32_bf16(pf, v1, O1, 0, 0, 0);
        }
    }
    #pragma unroll
    for (int r = 0; r < 4; r++) {
        const float inv = 1.0f / l_r[r];
        const int i = i0 + l4 * 4 + r;
        unsigned short* crow = &ctx[((size_t)b * NN + i) * D_MODEL + h * HEAD_DIM];
        crow[l16]      = f2bf(O0[r] * inv);
        crow[16 + l16] = f2bf(O1[r] * inv);
    }
}

// ---------------------------------------------------------------------------
// K5/K7/K8: register-direct bf16 MFMA GEMM. C = A @ W^T + bias (+res)(relu).
// A: M x KDIM bf16 row-major; W: N x KDIM bf16 row-major; out fp32 or bf16.
// Block 64x64 (4 waves 2x2), wave 32x32 = 2x2 MFMAs per 32-K step.
// ---------------------------------------------------------------------------
template <int KDIM, bool RELU, bool HASRES, bool OUTBF>
__global__ __launch_bounds__(256)
void mfma_gemm(const unsigned short* __restrict__ A, const unsigned short* __restrict__ W,
               const float* __restrict__ bias, const float* __restrict__ res,
               float* __restrict__ outf, unsigned short* __restrict__ outb, int N) {
    const int w    = threadIdx.x >> 6;
    const int lane = threadIdx.x & 63;
    const int l16 = lane & 15, l4 = lane >> 4;
    const int n0 = blockIdx.x * 64;
    const int m0 = blockIdx.y * 64;
    const int wm = (w >> 1) * 32, wn = (w & 1) * 32;

    const unsigned short* Ar = &A[(size_t)(m0 + wm + l16) * KDIM];
    const unsigned short* Wr = &W[(size_t)(n0 + wn + l16) * KDIM];

    f32x4 acc[2][2] = {};
    #pragma unroll 8
    for (int k0 = 0; k0 < KDIM; k0 += 32) {
        bf16x8 a0 = *(const bf16x8*)&Ar[k0 + l4 * 8];
        bf16x8 a1 = *(const bf16x8*)&Ar[16 * KDIM + k0 + l4 * 8];
        bf16x8 b0 = *(const bf16x8*)&Wr[k0 + l4 * 8];
        bf16x8 b1 = *(const bf16x8*)&Wr[16 * KDIM + k0 + l4 * 8];
        acc[0][0] = __builtin_amdgcn_mfma_f32_16x16x32_bf16(a0, b0, acc[0][0], 0, 0, 0);
        acc[0][1] = __builtin_amdgcn_mfma_f32_16x16x32_bf16(a0, b1, acc[0][1], 0, 0, 0);
        acc[1][0] = __builtin_amdgcn_mfma_f32_16x16x32_bf16(a1, b0, acc[1][0], 0, 0, 0);
        acc[1][1] = __builtin_amdgcn_mfma_f32_16x16x32_bf16(a1, b1, acc[1][1], 0, 0, 0);
    }

    #pragma unroll
    for (int i = 0; i < 2; i++) {
        #pragma unroll
        for (int j = 0; j < 2; j++) {
            const int c = n0 + wn + j * 16 + l16;
            const float bs = bias[c];
            #pragma unroll
            for (int r = 0; r < 4; r++) {
                const int m = m0 + wm + i * 16 + l4 * 4 + r;
                float v = acc[i][j][r] + bs;
                if (RELU) v = fmaxf(v, 0.f);
                if (HASRES) v += res[(size_t)m * N + c];
                if (OUTBF) outb[(size_t)m * N + c] = f2bf(v);
                else       outf[(size_t)m * N + c] = v;
            }
        }
    }
}

// ---------------------------------------------------------------------------
// K6/K9: LayerNorm over rows of 256; optionally also emits bf16 copy.
// ---------------------------------------------------------------------------
template <bool WBF>
__global__ __launch_bounds__(256)
void ln_kernel(const float* __restrict__ y, const float* __restrict__ g,
               const float* __restrict__ beta, float* __restrict__ o,
               unsigned short* __restrict__ obf) {
    const int row = blockIdx.x;
    const float v = y[(size_t)row * D_MODEL + threadIdx.x];
    float s = v, sq = v * v;
    #pragma unroll
    for (int mask = 1; mask < 64; mask <<= 1) {
        s  += __shfl_xor(s, mask, 64);
        sq += __shfl_xor(sq, mask, 64);
    }
    __shared__ float rs_[4], rq_[4];
    const int w = threadIdx.x >> 6;
    if ((threadIdx.x & 63) == 0) { rs_[w] = s; rq_[w] = sq; }
    __syncthreads();
    s  = rs_[0] + rs_[1] + rs_[2] + rs_[3];
    sq = rq_[0] + rq_[1] + rq_[2] + rq_[3];
    const float mu = s * (1.0f / D_MODEL);
    const float var = sq * (1.0f / D_MODEL) - mu * mu;
    const float rstd = rsqrtf(var + LN_EPS);
    const float ov = (v - mu) * rstd * g[threadIdx.x] + beta[threadIdx.x];
    o[(size_t)row * D_MODEL + threadIdx.x] = ov;
    if (WBF) obf[(size_t)row * D_MODEL + threadIdx.x] = f2bf(ov);
}

// ---------------------------------------------------------------------------
// launch
// ---------------------------------------------------------------------------
extern "C" void kernel_launch(void* const* d_in, const int* in_sizes, int n_in,
                              void* d_out, int out_size, void* d_ws, size_t ws_size,
                              hipStream_t stream) {
    const float* embed     = (const float*)d_in[0];
    const float* dist      = (const float*)d_in[2];
    const float* query_pos = (const float*)d_in[3];
    const float* in_proj_w = (const float*)d_in[4];
    const float* in_proj_b = (const float*)d_in[5];
    const float* out_w     = (const float*)d_in[6];
    const float* out_b     = (const float*)d_in[7];
    const float* tau_w     = (const float*)d_in[8];
    const float* tau_b     = (const float*)d_in[9];
    const float* w1        = (const float*)d_in[10];
    const float* b1        = (const float*)d_in[11];
    const float* w2        = (const float*)d_in[12];
    const float* b2        = (const float*)d_in[13];
    const float* g1        = (const float*)d_in[14];
    const float* beta1     = (const float*)d_in[15];
    const float* g2        = (const float*)d_in[16];
    const float* beta2     = (const float*)d_in[17];
    float* out = (float*)d_out;

    char* ws = (char*)d_ws;
    const size_t MB = 1024 * 1024;
    unsigned short* emb_bf  = (unsigned short*)(ws);             // 2 MB
    unsigned short* qk_bf   = (unsigned short*)(ws + 2 * MB);    // 2 MB
    unsigned short* qb      = (unsigned short*)(ws + 4 * MB);    // 2 MB
    unsigned short* kb      = (unsigned short*)(ws + 6 * MB);    // 2 MB
    unsigned short* vbT     = (unsigned short*)(ws + 8 * MB);    // 2 MB
    float*          taub    = (float*)(ws + 10 * MB);            // 128 KB
    unsigned short* ctx_bf  = (unsigned short*)(ws + 11 * MB);   // 2 MB
    float*          y1      = (float*)(ws + 13 * MB);            // 4 MB
    float*          x       = (float*)(ws + 17 * MB);            // 4 MB
    unsigned short* x_bf    = (unsigned short*)(ws + 21 * MB);   // 2 MB
    unsigned short* ffn_bf  = (unsigned short*)(ws + 23 * MB);   // 8 MB
    float*          y2      = (float*)(ws + 31 * MB);            // 4 MB
    unsigned short* inw_bf  = (unsigned short*)(ws + 35 * MB);   // 384 KB
    unsigned short* outw_bf = (unsigned short*)(ws + 36 * MB);   // 128 KB
    unsigned short* w1_bf   = (unsigned short*)(ws + 37 * MB);   // 512 KB
    unsigned short* w2_bf   = (unsigned short*)(ws + 38 * MB);   // 512 KB
    unsigned short* taupad  = (unsigned short*)(ws + 39 * MB);   // 32 KB

    // K1: bf16 activations (embed, embed+query_pos)
    prep_kernel<<<dim3(1024), dim3(256), 0, stream>>>(
        (const float4*)embed, (const float4*)query_pos,
        (ushort4*)emb_bf, (ushort4*)qk_bf, M_TOT * D_MODEL / 4);

    // K2: bf16 weights (+ zero-padded tau tile)
    cvt_w_kernel<<<dim3(784), dim3(256), 0, stream>>>(
        (const float4*)in_proj_w, (const float4*)out_w, (const float4*)w1,
        (const float4*)w2, (const float4*)tau_w,
        (ushort4*)inw_bf, (ushort4*)outw_bf, (ushort4*)w1_bf, (ushort4*)w2_bf,
        (ushort4*)taupad);

    // K3: qkv + tau MFMA GEMM
    qkv_mfma_kernel<<<dim3(13, M_TOT / 64), dim3(256), 0, stream>>>(
        qk_bf, emb_bf, inw_bf, taupad, in_proj_b, tau_b, qb, kb, vbT, taub);

    // K4: flash MFMA attention -> ctx bf16
    attn_mfma_kernel<<<dim3(NN / 64, BB * N_HEADS), dim3(256), 0, stream>>>(
        qb, kb, vbT, taub, dist, ctx_bf);

    // K5: y1 = ctx @ out_w^T + out_b + embed   (fp32 out)
    mfma_gemm<D_MODEL, false, true, false><<<dim3(4, 64), dim3(256), 0, stream>>>(
        ctx_bf, outw_bf, out_b, embed, y1, nullptr, D_MODEL);

    // K6: x = LN(y1)  (+ bf16 copy)
    ln_kernel<true><<<dim3(M_TOT), dim3(256), 0, stream>>>(y1, g1, beta1, x, x_bf);

    // K7: ffn = relu(x @ w1^T + b1)  (bf16 out)
    mfma_gemm<D_MODEL, true, false, true><<<dim3(16, 64), dim3(256), 0, stream>>>(
        x_bf, w1_bf, b1, nullptr, nullptr, ffn_bf, D_FFN);

    // K8: y2 = ffn @ w2^T + b2 + x  (fp32 out)
    mfma_gemm<D_FFN, false, true, false><<<dim3(4, 64), dim3(256), 0, stream>>>(
        ffn_bf, w2_bf, b2, x, y2, nullptr, D_MODEL);

    // K9: out = LN(y2)
    ln_kernel<false><<<dim3(M_TOT), dim3(256), 0, stream>>>(y2, g2, beta2, out, nullptr);
}